// Round 13
// baseline (71.949 us; speedup 1.0000x reference)
//
#include <hip/hip_runtime.h>
#include <hip/hip_fp16.h>

#define EMB 128
#define KN 16
#define NREL 32

__device__ __forceinline__ float fast_tanh(float x) {
    // exact identity tanh(x) = 1 - 2/(e^{2x}+1); v_exp-based, ~1e-6 abs err.
    const float z = __expf(2.0f * x);
    return 1.0f - __fdividef(2.0f, z + 1.0f);
}

__device__ __forceinline__ float4 fma4(float s, float4 v, float4 a) {
    a.x = fmaf(s, v.x, a.x); a.y = fmaf(s, v.y, a.y);
    a.z = fmaf(s, v.z, a.z); a.w = fmaf(s, v.w, a.w);
    return a;
}

// ---------------- prep: role-split grid -------------------------------------
// blocks [0,256): costab (4 pairs/block = 1024 pairs)
// blocks [256, ..): node_table fp32 -> fp16 grid-stride convert
__global__ __launch_bounds__(256) void pgra_prep(
    const float* __restrict__ node_table, __half* __restrict__ nt16, int n8,
    const float* __restrict__ rela, float* __restrict__ costab)
{
    if (blockIdx.x < 256) {
        const int pair = blockIdx.x * 4 + (threadIdx.x >> 6);
        const int lane = threadIdx.x & 63;
        const int r = pair >> 5, c = pair & 31;
        const float2 av = ((const float2*)(rela + (size_t)r * EMB))[lane];
        const float2 bv = ((const float2*)(rela + (size_t)c * EMB))[lane];
        float dot = av.x * bv.x + av.y * bv.y;
        float na  = av.x * av.x + av.y * av.y;
        float nb  = bv.x * bv.x + bv.y * bv.y;
        #pragma unroll
        for (int off = 32; off > 0; off >>= 1) {
            dot += __shfl_xor(dot, off);
            na  += __shfl_xor(na,  off);
            nb  += __shfl_xor(nb,  off);
        }
        if (lane == 0)
            costab[pair] = fabsf(dot / (sqrtf(na) * sqrtf(nb) + 1e-8f));
        return;
    }
    union { __half2 h; unsigned u; } c0, c1, c2, c3;
    const int stride = (gridDim.x - 256) * 256;
    for (int i = (blockIdx.x - 256) * 256 + threadIdx.x; i < n8; i += stride) {
        const float4 a = ((const float4*)node_table)[2 * i];
        const float4 b = ((const float4*)node_table)[2 * i + 1];
        c0.h = __float22half2_rn(make_float2(a.x, a.y));
        c1.h = __float22half2_rn(make_float2(a.z, a.w));
        c2.h = __float22half2_rn(make_float2(b.x, b.y));
        c3.h = __float22half2_rn(make_float2(b.z, b.w));
        uint4 o; o.x = c0.u; o.y = c1.u; o.z = c2.u; o.w = c3.u;
        ((uint4*)nt16)[i] = o;
    }
}

// ---------------- fused: gather (fp16) + W0 + hop-2 attn + W1, 1 b per block -
// 4 waves; wave w gathers its 4 (b,j) pairs sequentially (gather7 body) into
// s_agg; then 8 half-waves run the tail11-style k-split W0 stage and row-split
// W1 stage. No agg global round-trip, tail overlaps other blocks' gathers.
__global__ __launch_bounds__(256, 4) void pgra_one(
    const int* __restrict__ node, const int* __restrict__ relation,
    const int* __restrict__ adj_node, const int* __restrict__ adj_rela,
    const __half* __restrict__ nt16, const float* __restrict__ proj_table,
    const float* __restrict__ W0, const float* __restrict__ b0,
    const float* __restrict__ W1, const float* __restrict__ b1,
    const float* __restrict__ costab, float* __restrict__ out)
{
    const int b    = blockIdx.x;
    const int tid  = threadIdx.x;
    const int wave = tid >> 6;
    const int lane = tid & 63;

    __shared__ float s_agg[KN][EMB];   // 8 KB
    __shared__ float s_part[8][EMB];   // 4 KB
    __shared__ float s_fin[EMB];       // 0.5 KB

    const int n0  = node[b];           // uniform per block
    const int rel = relation[b];

    // ---- gather phase: wave handles j = 4*wave + jj, one at a time ----
    for (int jj = 0; jj < 4; ++jj) {
        const int j  = wave * 4 + jj;
        const int n1 = adj_node[n0 * KN + j];
        const int4* np = (const int4*)(adj_node + (size_t)n1 * KN);
        const int4* rp = (const int4*)(adj_rela + (size_t)n1 * KN);
        const int4 nn0 = np[0], nn1 = np[1], nn2 = np[2], nn3 = np[3];
        const int4 rr0 = rp[0], rr1 = rp[1], rr2 = rp[2], rr3 = rp[3];

        __half2 h0,h1,h2,h3,h4,h5,h6,h7,h8,h9,h10,h11,h12,h13,h14,h15;
        h0  = ((const __half2*)(nt16 + (size_t)nn0.x * EMB))[lane];
        h1  = ((const __half2*)(nt16 + (size_t)nn0.y * EMB))[lane];
        h2  = ((const __half2*)(nt16 + (size_t)nn0.z * EMB))[lane];
        h3  = ((const __half2*)(nt16 + (size_t)nn0.w * EMB))[lane];
        h4  = ((const __half2*)(nt16 + (size_t)nn1.x * EMB))[lane];
        h5  = ((const __half2*)(nt16 + (size_t)nn1.y * EMB))[lane];
        h6  = ((const __half2*)(nt16 + (size_t)nn1.z * EMB))[lane];
        h7  = ((const __half2*)(nt16 + (size_t)nn1.w * EMB))[lane];
        h8  = ((const __half2*)(nt16 + (size_t)nn2.x * EMB))[lane];
        h9  = ((const __half2*)(nt16 + (size_t)nn2.y * EMB))[lane];
        h10 = ((const __half2*)(nt16 + (size_t)nn2.z * EMB))[lane];
        h11 = ((const __half2*)(nt16 + (size_t)nn2.w * EMB))[lane];
        h12 = ((const __half2*)(nt16 + (size_t)nn3.x * EMB))[lane];
        h13 = ((const __half2*)(nt16 + (size_t)nn3.y * EMB))[lane];
        h14 = ((const __half2*)(nt16 + (size_t)nn3.z * EMB))[lane];
        h15 = ((const __half2*)(nt16 + (size_t)nn3.w * EMB))[lane];

        float sc[KN];
        sc[0]  = costab[rr0.x * NREL + rel]; sc[1]  = costab[rr0.y * NREL + rel];
        sc[2]  = costab[rr0.z * NREL + rel]; sc[3]  = costab[rr0.w * NREL + rel];
        sc[4]  = costab[rr1.x * NREL + rel]; sc[5]  = costab[rr1.y * NREL + rel];
        sc[6]  = costab[rr1.z * NREL + rel]; sc[7]  = costab[rr1.w * NREL + rel];
        sc[8]  = costab[rr2.x * NREL + rel]; sc[9]  = costab[rr2.y * NREL + rel];
        sc[10] = costab[rr2.z * NREL + rel]; sc[11] = costab[rr2.w * NREL + rel];
        sc[12] = costab[rr3.x * NREL + rel]; sc[13] = costab[rr3.y * NREL + rel];
        sc[14] = costab[rr3.z * NREL + rel]; sc[15] = costab[rr3.w * NREL + rel];

        float m = sc[0];
        #pragma unroll
        for (int k = 1; k < KN; ++k) m = fmaxf(m, sc[k]);
        float sum = 0.f;
        #pragma unroll
        for (int k = 0; k < KN; ++k) { sc[k] = __expf(sc[k] - m); sum += sc[k]; }
        const float inv = __fdividef(1.f, sum);

        float ax = 0.f, ay = 0.f;
        float2 v;
        v = __half22float2(h0);  ax = fmaf(sc[0],  v.x, ax); ay = fmaf(sc[0],  v.y, ay);
        v = __half22float2(h1);  ax = fmaf(sc[1],  v.x, ax); ay = fmaf(sc[1],  v.y, ay);
        v = __half22float2(h2);  ax = fmaf(sc[2],  v.x, ax); ay = fmaf(sc[2],  v.y, ay);
        v = __half22float2(h3);  ax = fmaf(sc[3],  v.x, ax); ay = fmaf(sc[3],  v.y, ay);
        v = __half22float2(h4);  ax = fmaf(sc[4],  v.x, ax); ay = fmaf(sc[4],  v.y, ay);
        v = __half22float2(h5);  ax = fmaf(sc[5],  v.x, ax); ay = fmaf(sc[5],  v.y, ay);
        v = __half22float2(h6);  ax = fmaf(sc[6],  v.x, ax); ay = fmaf(sc[6],  v.y, ay);
        v = __half22float2(h7);  ax = fmaf(sc[7],  v.x, ax); ay = fmaf(sc[7],  v.y, ay);
        v = __half22float2(h8);  ax = fmaf(sc[8],  v.x, ax); ay = fmaf(sc[8],  v.y, ay);
        v = __half22float2(h9);  ax = fmaf(sc[9],  v.x, ax); ay = fmaf(sc[9],  v.y, ay);
        v = __half22float2(h10); ax = fmaf(sc[10], v.x, ax); ay = fmaf(sc[10], v.y, ay);
        v = __half22float2(h11); ax = fmaf(sc[11], v.x, ax); ay = fmaf(sc[11], v.y, ay);
        v = __half22float2(h12); ax = fmaf(sc[12], v.x, ax); ay = fmaf(sc[12], v.y, ay);
        v = __half22float2(h13); ax = fmaf(sc[13], v.x, ax); ay = fmaf(sc[13], v.y, ay);
        v = __half22float2(h14); ax = fmaf(sc[14], v.x, ax); ay = fmaf(sc[14], v.y, ay);
        v = __half22float2(h15); ax = fmaf(sc[15], v.x, ax); ay = fmaf(sc[15], v.y, ay);

        const float2 pj = ((const float2*)(proj_table + (size_t)rel * EMB))[lane];
        s_agg[j][2 * lane]     = ax * inv * pj.x;
        s_agg[j][2 * lane + 1] = ay * inv * pj.y;
    }
    __syncthreads();

    // ---- W0 stage: 8 half-waves, half-wave hw owns k = {2hw, 2hw+1} ----
    const int c  = lane & 31;          // col quad 4c..4c+3
    const int hw = wave * 2 + (lane >> 5);
    const int k0 = hw * 2;

    const float4 bias = *(const float4*)&b0[4 * c];
    float4 acc0 = bias, acc1 = bias;
    for (int ee4 = 0; ee4 < 32; ++ee4) {
        const int row = 4 * ee4;
        float4 w0q[4];
        #pragma unroll
        for (int r = 0; r < 4; ++r)
            w0q[r] = *(const float4*)&W0[(row + r) * EMB + 4 * c];
        const float4 a0 = *(const float4*)&s_agg[k0][row];      // broadcast
        const float4 a1 = *(const float4*)&s_agg[k0 + 1][row];  // broadcast
        acc0 = fma4(a0.x, w0q[0], fma4(a0.y, w0q[1], fma4(a0.z, w0q[2], fma4(a0.w, w0q[3], acc0))));
        acc1 = fma4(a1.x, w0q[0], fma4(a1.y, w0q[1], fma4(a1.z, w0q[2], fma4(a1.w, w0q[3], acc1))));
    }

    // hop-2 attention weights (uniform) + tanh fold over this half-wave's 2 k's
    float sc0[KN];
    {
        const int4* r0p = (const int4*)(adj_rela + (size_t)n0 * KN);
        #pragma unroll
        for (int q = 0; q < 4; ++q) {
            const int4 rr = r0p[q];
            sc0[4*q+0] = costab[rr.x * NREL + rel];
            sc0[4*q+1] = costab[rr.y * NREL + rel];
            sc0[4*q+2] = costab[rr.z * NREL + rel];
            sc0[4*q+3] = costab[rr.w * NREL + rel];
        }
    }
    float m = sc0[0];
    #pragma unroll
    for (int k = 1; k < KN; ++k) m = fmaxf(m, sc0[k]);
    float sum = 0.f;
    #pragma unroll
    for (int k = 0; k < KN; ++k) { sc0[k] = __expf(sc0[k] - m); sum += sc0[k]; }
    const float inv = __fdividef(1.f, sum);

    {
        const float wA = sc0[k0] * inv, wB = sc0[k0 + 1] * inv;
        float4 part;
        part.x = fmaf(wA, fast_tanh(acc0.x), wB * fast_tanh(acc1.x));
        part.y = fmaf(wA, fast_tanh(acc0.y), wB * fast_tanh(acc1.y));
        part.z = fmaf(wA, fast_tanh(acc0.z), wB * fast_tanh(acc1.z));
        part.w = fmaf(wA, fast_tanh(acc0.w), wB * fast_tanh(acc1.w));
        *(float4*)&s_part[hw][4 * c] = part;
    }
    __syncthreads();

    if (tid < EMB) {
        float fin = 0.f;
        #pragma unroll
        for (int q = 0; q < 8; ++q) fin += s_part[q][tid];
        s_fin[tid] = fin;
    }
    __syncthreads();

    // ---- W1 stage: half-wave hw owns rows 16hw..16hw+15 ----
    float4 o = make_float4(0.f, 0.f, 0.f, 0.f);
    #pragma unroll
    for (int i = 0; i < 4; ++i) {
        const int row = hw * 16 + 4 * i;
        const float4 f = *(const float4*)&s_fin[row];           // broadcast
        float4 w1q[4];
        #pragma unroll
        for (int r = 0; r < 4; ++r)
            w1q[r] = *(const float4*)&W1[(row + r) * EMB + 4 * c];
        o = fma4(f.x, w1q[0], fma4(f.y, w1q[1], fma4(f.z, w1q[2], fma4(f.w, w1q[3], o))));
    }
    *(float4*)&s_part[hw][4 * c] = o;
    __syncthreads();

    if (tid < EMB) {
        float v = b1[tid];
        #pragma unroll
        for (int q = 0; q < 8; ++q) v += s_part[q][tid];
        out[(size_t)b * EMB + tid] = fast_tanh(v);
    }
}

// ---------------- costab standalone (for fallback path) ---------------------
__global__ __launch_bounds__(256) void pgra_costab_k(const float* __restrict__ rela,
                                                     float* __restrict__ costab) {
    const int pair = blockIdx.x * 4 + (threadIdx.x >> 6);
    const int lane = threadIdx.x & 63;
    const int r = pair >> 5, c = pair & 31;
    const float2 av = ((const float2*)(rela + (size_t)r * EMB))[lane];
    const float2 bv = ((const float2*)(rela + (size_t)c * EMB))[lane];
    float dot = av.x * bv.x + av.y * bv.y;
    float na  = av.x * av.x + av.y * av.y;
    float nb  = bv.x * bv.x + bv.y * bv.y;
    #pragma unroll
    for (int off = 32; off > 0; off >>= 1) {
        dot += __shfl_xor(dot, off);
        na  += __shfl_xor(na,  off);
        nb  += __shfl_xor(nb,  off);
    }
    if (lane == 0)
        costab[pair] = fabsf(dot / (sqrtf(na) * sqrtf(nb) + 1e-8f));
}

// ---------------- Fallback fused fp32 kernel (round-3/4 verified) -----------
__global__ __launch_bounds__(1024) void pgra_fused(
    const int* __restrict__ node, const int* __restrict__ relation,
    const int* __restrict__ adj_node, const int* __restrict__ adj_rela,
    const float* __restrict__ node_table, const float* __restrict__ proj_table,
    const float* __restrict__ W0, const float* __restrict__ b0,
    const float* __restrict__ W1, const float* __restrict__ b1,
    const float* __restrict__ costab, float* __restrict__ out)
{
    const int b    = blockIdx.x;
    const int tid  = threadIdx.x;
    const int wave = tid >> 6;
    const int lane = tid & 63;

    __shared__ float s_agg[KN][EMB];
    __shared__ float s_part[2][EMB];
    __shared__ float s_fin[EMB];

    const int n0  = node[b];
    const int rel = relation[b];

    {
        const int j  = wave;
        const int n1 = adj_node[n0 * KN + j];
        const int4* n2p = (const int4*)(adj_node + (size_t)n1 * KN);
        const int4* r1p = (const int4*)(adj_rela + (size_t)n1 * KN);
        int   n2[KN];
        float sc[KN];
        #pragma unroll
        for (int q = 0; q < 4; ++q) {
            const int4 nn = n2p[q];
            const int4 rr = r1p[q];
            n2[4*q+0] = nn.x; n2[4*q+1] = nn.y; n2[4*q+2] = nn.z; n2[4*q+3] = nn.w;
            sc[4*q+0] = costab[rr.x * NREL + rel];
            sc[4*q+1] = costab[rr.y * NREL + rel];
            sc[4*q+2] = costab[rr.z * NREL + rel];
            sc[4*q+3] = costab[rr.w * NREL + rel];
        }
        float m = sc[0];
        #pragma unroll
        for (int k = 1; k < KN; ++k) m = fmaxf(m, sc[k]);
        float sum = 0.f;
        #pragma unroll
        for (int k = 0; k < KN; ++k) { sc[k] = __expf(sc[k] - m); sum += sc[k]; }
        const float inv = 1.f / sum;
        float ax = 0.f, ay = 0.f;
        #pragma unroll
        for (int k = 0; k < KN; ++k) {
            const float2 v = ((const float2*)(node_table + (size_t)n2[k] * EMB))[lane];
            ax = fmaf(sc[k], v.x, ax);
            ay = fmaf(sc[k], v.y, ay);
        }
        const float2 pj = ((const float2*)(proj_table + (size_t)rel * EMB))[lane];
        s_agg[j][2*lane]   = ax * inv * pj.x;
        s_agg[j][2*lane+1] = ay * inv * pj.y;
    }
    __syncthreads();

    if (tid < 256) {
        const int e  = tid & 127;
        const int g  = tid >> 7;
        const int jg = g * 8;
        float acc[8];
        const float bias = b0[e];
        #pragma unroll
        for (int q = 0; q < 8; ++q) acc[q] = bias;
        for (int ee4 = 0; ee4 < EMB / 4; ++ee4) {
            const float w0v = W0[(4 * ee4 + 0) * EMB + e];
            const float w1v = W0[(4 * ee4 + 1) * EMB + e];
            const float w2v = W0[(4 * ee4 + 2) * EMB + e];
            const float w3v = W0[(4 * ee4 + 3) * EMB + e];
            #pragma unroll
            for (int q = 0; q < 8; ++q) {
                const float4 a = *(const float4*)&s_agg[jg + q][4 * ee4];
                acc[q] = fmaf(a.x, w0v, fmaf(a.y, w1v, fmaf(a.z, w2v, fmaf(a.w, w3v, acc[q]))));
            }
        }
        float sc0[KN];
        float m = -1e30f;
        #pragma unroll
        for (int k = 0; k < KN; ++k) {
            sc0[k] = costab[adj_rela[n0 * KN + k] * NREL + rel];
            m = fmaxf(m, sc0[k]);
        }
        float sum = 0.f;
        #pragma unroll
        for (int k = 0; k < KN; ++k) { sc0[k] = __expf(sc0[k] - m); sum += sc0[k]; }
        const float inv = 1.f / sum;
        float part = 0.f;
        #pragma unroll
        for (int q = 0; q < 8; ++q)
            part = fmaf(sc0[jg + q] * inv, fast_tanh(acc[q]), part);
        s_part[g][e] = part;
    }
    __syncthreads();

    if (tid < EMB) s_fin[tid] = s_part[0][tid] + s_part[1][tid];
    __syncthreads();

    if (tid < EMB) {
        float acc = b1[tid];
        for (int ee = 0; ee < EMB; ++ee) acc = fmaf(s_fin[ee], W1[ee * EMB + tid], acc);
        out[(size_t)b * EMB + tid] = fast_tanh(acc);
    }
}

extern "C" void kernel_launch(void* const* d_in, const int* in_sizes, int n_in,
                              void* d_out, int out_size, void* d_ws, size_t ws_size,
                              hipStream_t stream) {
    const int*   node       = (const int*)d_in[0];
    const int*   relation   = (const int*)d_in[1];
    const int*   adj_node   = (const int*)d_in[2];
    const int*   adj_rela   = (const int*)d_in[3];
    const float* node_table = (const float*)d_in[4];
    const float* rela_table = (const float*)d_in[5];
    const float* proj_table = (const float*)d_in[6];
    const float* W0         = (const float*)d_in[7];
    const float* b0         = (const float*)d_in[8];
    const float* W1         = (const float*)d_in[9];
    const float* b1         = (const float*)d_in[10];
    float* outp = (float*)d_out;
    const int B  = in_sizes[0];
    const int NN = in_sizes[4] / EMB;

    float*  costab = (float*)d_ws;                       // 4 KB
    __half* nt16   = (__half*)((char*)d_ws + 4096);      // NN*128 fp16

    const size_t need = 4096 + (size_t)NN * EMB * sizeof(__half);

    if (ws_size >= need) {
        const int n8 = NN * EMB / 8;
        hipLaunchKernelGGL(pgra_prep, dim3(256 + 2048), dim3(256), 0, stream,
                           node_table, nt16, n8, rela_table, costab);
        hipLaunchKernelGGL(pgra_one, dim3(B), dim3(256), 0, stream,
                           node, relation, adj_node, adj_rela,
                           nt16, proj_table, W0, b0, W1, b1, costab, outp);
    } else {
        hipLaunchKernelGGL(pgra_costab_k, dim3(NREL * NREL / 4), dim3(256), 0, stream,
                           rela_table, costab);
        hipLaunchKernelGGL(pgra_fused, dim3(B), dim3(1024), 0, stream,
                           node, relation, adj_node, adj_rela,
                           node_table, proj_table, W0, b0, W1, b1, costab, outp);
    }
}